// Round 4
// baseline (321.625 us; speedup 1.0000x reference)
//
#include <hip/hip_runtime.h>
#include <hip/hip_bf16.h>

typedef __bf16 bf16_t;
typedef __bf16 bf16x8 __attribute__((ext_vector_type(8)));
typedef __bf16 bf16x4 __attribute__((ext_vector_type(4)));
typedef float f32x4 __attribute__((ext_vector_type(4)));

#define NUM_USER 200000
#define NUM_ITEM 200000
#define DIM_E 64
#define DIM_FEAT 128
#define HID 256
#define BATCH 16384
#define GG 17
#define NN (BATCH * GG)   // 278528
#define NREP 139264       // int(NN * 0.5)
#define HP 40             // h-strip LDS pitch (bf16)
#define W1P 136           // W1 panel LDS pitch (bf16): 68 words -> uniform banks

// ---------------------------------------------------------------------------
// K1: transpose + bf16-cast weights (fragments want N-major), scatter mask
// ---------------------------------------------------------------------------
__global__ __launch_bounds__(256) void prep2_kernel(
    const float* __restrict__ W1, const float* __restrict__ W2,
    const int* __restrict__ rand_index,
    bf16_t* __restrict__ W1t, bf16_t* __restrict__ W2t,
    unsigned char* __restrict__ mask)
{
    const int t = blockIdx.x * 256 + threadIdx.x;
    if (t < HID * DIM_FEAT) {            // W1t[n][k], n<256, k<128
        const int n = t >> 7, k = t & 127;
        W1t[t] = (bf16_t)W1[k * HID + n];
    }
    if (t < DIM_E * HID) {               // W2t[n][k], n<64, k<256
        const int n = t >> 8, k = t & 255;
        W2t[t] = (bf16_t)W2[k * DIM_E + n];
    }
    if (t < NREP) mask[rand_index[t]] = 1;
}

// ---------------------------------------------------------------------------
// K2: encoder v4. Block = 64 rows, wave = 16 rows. W1 staged per-p as a
//   double-buffered LDS panel (32 n-rows x 128 k), shared by all 4 waves.
//   ~90 VGPR -> 4 waves/SIMD. feature written as bf16.
// ---------------------------------------------------------------------------
__global__ __launch_bounds__(256, 4) void encoder4_kernel(
    const float* __restrict__ vfeat,
    const bf16_t* __restrict__ W1t, const float* __restrict__ b1v,
    const bf16_t* __restrict__ W2t, const float* __restrict__ b2v,
    bf16_t* __restrict__ featB)
{
    const int tid  = threadIdx.x;
    const int wave = tid >> 6;
    const int lane = tid & 63;
    const int m    = lane & 15;
    const int quad = lane >> 4;
    const int row0 = blockIdx.x * 64;          // block tile (3125*64 == 200000)
    const int srow = row0 + wave * 16;         // this wave's strip

    __shared__ bf16_t pan[2][32 * W1P];
    __shared__ bf16_t hst[4][16 * HP];

    // staging geometry: 256 threads x 2 passes cover 32 rows x 256B
    const int sr0 = tid >> 4;          // rows 0..15
    const int seg = tid & 15;          // 16B segment
    const int e0  = sr0 * DIM_FEAT + seg * 8;          // bf16 offset in panel source
    const int d0  = sr0 * W1P + seg * 8;               // bf16 offset in LDS panel
    const int e1  = e0 + 16 * DIM_FEAT;
    const int d1  = d0 + 16 * W1P;

    // ---- stage panel 0 (issue loads now, write after A-phase compute) ----
    float4 st0 = *reinterpret_cast<const float4*>(W1t + e0);
    float4 st1 = *reinterpret_cast<const float4*>(W1t + e1);

    // ---- A-phase: load 16 rows of v_feat, fused l2norm, bf16 fragments ----
    const float* rp = vfeat + (size_t)(srow + m) * DIM_FEAT + quad * 8;
    float4 v0[4], v1[4];
#pragma unroll
    for (int ks = 0; ks < 4; ++ks) {
        v0[ks] = *reinterpret_cast<const float4*>(rp + ks * 32);
        v1[ks] = *reinterpret_cast<const float4*>(rp + ks * 32 + 4);
    }
    float ss = 0.f;
#pragma unroll
    for (int ks = 0; ks < 4; ++ks) {
        ss += v0[ks].x * v0[ks].x + v0[ks].y * v0[ks].y
            + v0[ks].z * v0[ks].z + v0[ks].w * v0[ks].w;
        ss += v1[ks].x * v1[ks].x + v1[ks].y * v1[ks].y
            + v1[ks].z * v1[ks].z + v1[ks].w * v1[ks].w;
    }
    ss += __shfl_xor(ss, 16, 64);
    ss += __shfl_xor(ss, 32, 64);
    const float inv = 1.0f / fmaxf(sqrtf(ss), 1e-12f);
    bf16x8 af[4];
#pragma unroll
    for (int ks = 0; ks < 4; ++ks) {
        bf16x8 v;
        v[0] = (bf16_t)(v0[ks].x * inv); v[1] = (bf16_t)(v0[ks].y * inv);
        v[2] = (bf16_t)(v0[ks].z * inv); v[3] = (bf16_t)(v0[ks].w * inv);
        v[4] = (bf16_t)(v1[ks].x * inv); v[5] = (bf16_t)(v1[ks].y * inv);
        v[6] = (bf16_t)(v1[ks].z * inv); v[7] = (bf16_t)(v1[ks].w * inv);
        af[ks] = v;
    }

    // commit panel 0
    *reinterpret_cast<float4*>(&pan[0][d0]) = st0;
    *reinterpret_cast<float4*>(&pan[0][d1]) = st1;
    __syncthreads();

    bf16_t* hw = hst[wave];
    f32x4 acc2[4];
#pragma unroll
    for (int n2 = 0; n2 < 4; ++n2) acc2[n2] = (f32x4){0.f, 0.f, 0.f, 0.f};

    for (int p = 0; p < 8; ++p) {
        const int cur = p & 1;
        // prefetch next panel to registers (in flight during compute)
        float4 nx0, nx1;
        if (p < 7) {
            const bf16_t* nsrc = W1t + (p + 1) * (32 * DIM_FEAT);
            nx0 = *reinterpret_cast<const float4*>(nsrc + e0);
            nx1 = *reinterpret_cast<const float4*>(nsrc + e1);
        }
        // ---- phase 1: h cols [p*32, p*32+32) for this wave's 16 rows ----
#pragma unroll
        for (int h = 0; h < 2; ++h) {
            const int nt = p * 2 + h;
            const bf16_t* bp = &pan[cur][(h * 16 + m) * W1P + quad * 8];
            bf16x8 bfr[4];
#pragma unroll
            for (int ks = 0; ks < 4; ++ks)
                bfr[ks] = *reinterpret_cast<const bf16x8*>(bp + ks * 32);
            const float4 bias1 = *reinterpret_cast<const float4*>(b1v + nt * 16 + quad * 4);
            f32x4 a1 = (f32x4){0.f, 0.f, 0.f, 0.f};
#pragma unroll
            for (int ks = 0; ks < 4; ++ks)   // A = W1 rows, B = act rows
                a1 = __builtin_amdgcn_mfma_f32_16x16x32_bf16(bfr[ks], af[ks], a1, 0, 0, 0);
            bf16x4 hv4;
#pragma unroll
            for (int i = 0; i < 4; ++i) {
                float hv = a1[i] + ((const float*)&bias1)[i];
                hv = hv >= 0.f ? hv : 0.01f * hv;
                hv4[i] = (bf16_t)hv;
            }
            // lane holds item-row m, h-cols (local) h*16+quad*4 .. +3
            *reinterpret_cast<bf16x4*>(hw + m * HP + h * 16 + quad * 4) = hv4;
        }
        // ---- phase 2: K-step over k in [p*32, p*32+32) ----
        bf16x8 b2f[4];
#pragma unroll
        for (int n2 = 0; n2 < 4; ++n2)
            b2f[n2] = *reinterpret_cast<const bf16x8*>(W2t + (n2 * 16 + m) * HID + p * 32 + quad * 8);
        const bf16x8 a2 = *reinterpret_cast<const bf16x8*>(hw + m * HP + quad * 8);
#pragma unroll
        for (int n2 = 0; n2 < 4; ++n2)
            acc2[n2] = __builtin_amdgcn_mfma_f32_16x16x32_bf16(b2f[n2], a2, acc2[n2], 0, 0, 0);
        // commit next panel + barrier
        if (p < 7) {
            *reinterpret_cast<float4*>(&pan[cur ^ 1][d0]) = nx0;
            *reinterpret_cast<float4*>(&pan[cur ^ 1][d1]) = nx1;
        }
        __syncthreads();
    }

    // ---- epilogue: bias + bf16 store ----
#pragma unroll
    for (int n2 = 0; n2 < 4; ++n2) {
        const float4 bias2 = *reinterpret_cast<const float4*>(b2v + n2 * 16 + quad * 4);
        bf16x4 o;
        o[0] = (bf16_t)(acc2[n2][0] + bias2.x);
        o[1] = (bf16_t)(acc2[n2][1] + bias2.y);
        o[2] = (bf16_t)(acc2[n2][2] + bias2.z);
        o[3] = (bf16_t)(acc2[n2][3] + bias2.w);
        *reinterpret_cast<bf16x4*>(featB + (size_t)(srow + m) * DIM_E + n2 * 16 + quad * 4) = o;
    }
}

// ---------------------------------------------------------------------------
// K3: normalized positive embeddings p_hat[b] = l2norm(id_emb[pos_b]), fp32
// ---------------------------------------------------------------------------
__global__ __launch_bounds__(256) void pnorm_kernel(
    const float* __restrict__ id_emb, const int* __restrict__ item_t,
    float* __restrict__ pnrm)
{
    const int kq = threadIdx.x & 3;
    const int r  = blockIdx.x * 64 + (threadIdx.x >> 2);
    const int pos = item_t[r * GG];
    const float4* pp = reinterpret_cast<const float4*>(id_emb + (size_t)pos * DIM_E) + kq * 4;
    float4 v[4];
    float ss = 0.f;
#pragma unroll
    for (int j = 0; j < 4; ++j) {
        v[j] = pp[j];
        ss += v[j].x * v[j].x + v[j].y * v[j].y + v[j].z * v[j].z + v[j].w * v[j].w;
    }
    ss += __shfl_xor(ss, 1, 64);
    ss += __shfl_xor(ss, 2, 64);
    const float inv = 1.0f / fmaxf(sqrtf(ss), 1e-12f);
    float4* op = reinterpret_cast<float4*>(pnrm + (size_t)r * DIM_E) + kq * 4;
#pragma unroll
    for (int j = 0; j < 4; ++j) {
        float4 o;
        o.x = v[j].x * inv; o.y = v[j].y * inv; o.z = v[j].z * inv; o.w = v[j].w * inv;
        op[j] = o;
    }
}

// ---------------------------------------------------------------------------
// K4: loss elements v3 — 4 lanes per (b,g); bf16 feature; p_hat table.
// ---------------------------------------------------------------------------
__global__ __launch_bounds__(256) void loss_elem3_kernel(
    const bf16_t* __restrict__ featB, const float* __restrict__ id_emb,
    const float* __restrict__ pnrm,
    const int* __restrict__ user_t, const int* __restrict__ item_t,
    const unsigned char* __restrict__ mask,
    float* __restrict__ s1, float* __restrict__ s2)
{
    const int kq = threadIdx.x & 3;          // dims [kq*16, kq*16+16)
    const int n  = blockIdx.x * 64 + (threadIdx.x >> 2);
    const int b  = n / GG;
    const int u  = user_t[n];
    const int it = item_t[n];
    int fidx = it - NUM_USER;
    fidx = min(max(fidx, 0), NUM_ITEM - 1);
    const bool rep = mask[n] != 0;

    const bf16x8* fp = reinterpret_cast<const bf16x8*>(featB + (size_t)fidx * DIM_E + kq * 16);
    const float4* ph = reinterpret_cast<const float4*>(pnrm + (size_t)b * DIM_E) + kq * 4;
    const float4* up = reinterpret_cast<const float4*>(id_emb + (size_t)u * DIM_E) + kq * 4;
    const float4* ip = reinterpret_cast<const float4*>(id_emb + (size_t)it * DIM_E) + kq * 4;

    float f[16];
#pragma unroll
    for (int h = 0; h < 2; ++h) {
        const bf16x8 fv = fp[h];
#pragma unroll
        for (int j = 0; j < 8; ++j) f[h * 8 + j] = (float)fv[j];
    }

    float x = 0.f, z = 0.f, w = 0.f;
#pragma unroll
    for (int j = 0; j < 4; ++j) {
        const float4 p = ph[j];
        const float4 uu = up[j];
        float4 a;
        if (rep) { a.x = f[j*4]; a.y = f[j*4+1]; a.z = f[j*4+2]; a.w = f[j*4+3]; }
        else     { a = ip[j]; }
        x += f[j*4]*f[j*4] + f[j*4+1]*f[j*4+1] + f[j*4+2]*f[j*4+2] + f[j*4+3]*f[j*4+3];
        z += p.x*f[j*4] + p.y*f[j*4+1] + p.z*f[j*4+2] + p.w*f[j*4+3];
        w += uu.x*a.x + uu.y*a.y + uu.z*a.z + uu.w*a.w;
    }
#pragma unroll
    for (int off = 1; off <= 2; off <<= 1) {
        x += __shfl_xor(x, off, 64);
        z += __shfl_xor(z, off, 64);
        w += __shfl_xor(w, off, 64);
    }
    if (kq == 0) {
        const float dot1 = z / fmaxf(sqrtf(x), 1e-12f);
        s1[n] = __expf(dot1 * 5.0f);   // 1/TEMP = 5
        s2[n] = __expf(w * 5.0f);
    }
}

// ---------------------------------------------------------------------------
// K5: per-b softmax-style loss + block reduce -> 64 partials
// ---------------------------------------------------------------------------
__global__ __launch_bounds__(256) void loss_reduce_kernel(
    const float* __restrict__ s1, const float* __restrict__ s2,
    float* __restrict__ partials)
{
    const int b = blockIdx.x * 256 + threadIdx.x;  // 64*256 == 16384 exactly
    float tot1 = 0.f, tot2 = 0.f, p1 = 0.f, p2 = 0.f;
#pragma unroll
    for (int g = 0; g < GG; ++g) {
        const float a1 = s1[b * GG + g];
        const float a2 = s2[b * GG + g];
        if (g == 0) { p1 = a1; p2 = a2; }
        tot1 += a1; tot2 += a2;
    }
    const float l1 = -logf(p1 / (tot1 + 1e-8f) + 1e-8f);
    const float l2 = -logf(p2 / (tot2 + 1e-8f) + 1e-8f);
    float v = 0.5f * l1 + 0.5f * l2;
#pragma unroll
    for (int off = 32; off > 0; off >>= 1) v += __shfl_xor(v, off, 64);
    __shared__ float red[4];
    const int wave = threadIdx.x >> 6, lane = threadIdx.x & 63;
    if (lane == 0) red[wave] = v;
    __syncthreads();
    if (threadIdx.x == 0) partials[blockIdx.x] = red[0] + red[1] + red[2] + red[3];
}

__global__ __launch_bounds__(64) void final_kernel(
    const float* __restrict__ partials, float* __restrict__ out)
{
    float v = partials[threadIdx.x];
#pragma unroll
    for (int off = 32; off > 0; off >>= 1) v += __shfl_xor(v, off, 64);
    if (threadIdx.x == 0) out[0] = v * (1.0f / BATCH);
}

// ---------------------------------------------------------------------------
extern "C" void kernel_launch(void* const* d_in, const int* in_sizes, int n_in,
                              void* d_out, int out_size, void* d_ws, size_t ws_size,
                              hipStream_t stream)
{
    (void)in_sizes; (void)n_in; (void)out_size; (void)ws_size;
    const float* v_feat    = (const float*)d_in[0];
    const float* id_emb    = (const float*)d_in[1];
    const float* W1        = (const float*)d_in[2];
    const float* b1        = (const float*)d_in[3];
    const float* W2        = (const float*)d_in[4];
    const float* b2        = (const float*)d_in[5];
    const int*   user_t    = (const int*)d_in[6];
    const int*   item_t    = (const int*)d_in[7];
    const int*   rand_idx  = (const int*)d_in[8];

    char* ws = (char*)d_ws;
    bf16_t*        W1t      = (bf16_t*)(ws + 0);             // 65536
    bf16_t*        W2t      = (bf16_t*)(ws + 65536);         // 32768
    unsigned char* mask     = (unsigned char*)(ws + 98304);  // 278528
    float*         s1       = (float*)(ws + 376832);         // 1114112
    float*         s2       = (float*)(ws + 1490944);        // 1114112
    float*         partials = (float*)(ws + 2605056);        // 256
    float*         pnrm     = (float*)(ws + 2605312);        // 4194304
    bf16_t*        featB    = (bf16_t*)(ws + 6799616);       // 25600000 -> 32.4 MB total

    hipMemsetAsync(mask, 0, NN, stream);
    prep2_kernel<<<544, 256, 0, stream>>>(W1, W2, rand_idx, W1t, W2t, mask);
    encoder4_kernel<<<3125, 256, 0, stream>>>(v_feat, W1t, b1, W2t, b2, featB);
    pnorm_kernel<<<256, 256, 0, stream>>>(id_emb, item_t, pnrm);
    loss_elem3_kernel<<<4352, 256, 0, stream>>>(featB, id_emb, pnrm, user_t, item_t, mask, s1, s2);
    loss_reduce_kernel<<<64, 256, 0, stream>>>(s1, s2, partials);
    final_kernel<<<1, 64, 0, stream>>>(partials, (float*)d_out);
}